// Round 10
// baseline (107.669 us; speedup 1.0000x reference)
//
#include <hip/hip_runtime.h>
#include <hip/hip_bf16.h>

// Chamfer loss: B=32, N=M=2048, D=3.
// loss[b] = 0.5 * ( sum_n ma[n]*min_m d2(a_n,b_m) + sum_m mb[m]*min_n d2(b_m,a_n) )
// masked pairs -> BIG^2 = 1e16.
//
// R10: MFMA path. R7/R9 proved the VALU loop is issue-bound at ~4 ops/pair and
// packing can't be expressed (compiler scalarizes v2f; asm adds copies). Move
// the 3 fma/pair onto the matrix pipe: d2_tile = A(16xK) x B(Kx16) via
// mfma_f32_16x16x32_bf16 with bf16 hi/lo error compensation (11 K-slots:
// {ah*bh, ah*bl, al*bh} per coord + 1*wh + 1*wl; dropped al*bl ~1e-5).
// VALU keeps only the min: 4 v_min per MFMA (floor ~3.4us device-wide).
// B-side fragments prepped into ws (4MB), read from L2. A-side built in regs.
// C/D layout col=lane&15,row=(lane>>4)*4+reg and A layout m=lane&15,k=quad*8+j
// are HW-verified (m89/m120); lanes with k>=16 supply zeros.
#define B_    32
#define N_    2048
#define M_    2048
#define BIG2  1.0e16f

typedef float f32x4  __attribute__((ext_vector_type(4)));
typedef short bf16x8 __attribute__((ext_vector_type(8)));

__device__ __forceinline__ short f2bf(float f) {
    unsigned u = __float_as_uint(f);
    u = (u + 0x7FFFu + ((u >> 16) & 1u)) >> 16;   // RN-even bf16
    return (short)u;
}
__device__ __forceinline__ float bf2f(short s) {
    return __uint_as_float(((unsigned)(unsigned short)s) << 16);
}

// ---- Prep: per (b,dir) build B-operand planes in ws.
// Layout: bd = b*2+dir; octet0 (k0-7) at bd*65536 + m*16, octet1 (k8-15) at
// +32768. Slots: [bxh,byh,bzh,bxl,byl,bzl,bxh,byh | bzh,wh,wl,0,0,0,0,0]
// where bh/bl split -2*b, wh/wl split (mask ? |b|^2 : 1e16).
__global__ __launch_bounds__(256) void chamfer_prep_mfma(
    const int* __restrict__ o_w, const float* __restrict__ o_pts,
    const int* __restrict__ t_w, const float* __restrict__ t_pts,
    char* __restrict__ wsB)
{
    int idx = blockIdx.x * 256 + threadIdx.x;   // 0 .. 131071
    int dir = idx >> 16;                        // B_*M_ = 65536
    int r   = idx & 65535;                      // b*M_ + m
    int b   = r >> 11;
    int m   = r & 2047;
    const int*   w = (dir == 0) ? t_w   : o_w;
    const float* p = (dir == 0) ? t_pts : o_pts;
    float x = p[r * 3 + 0], y = p[r * 3 + 1], z = p[r * 3 + 2];
    float b2 = fmaf(x, x, fmaf(y, y, z * z));
    float w2 = (w[r] != 0) ? b2 : BIG2;
    float nx = -2.f * x, ny = -2.f * y, nz = -2.f * z;
    short xh = f2bf(nx), yh = f2bf(ny), zh = f2bf(nz);
    short xl = f2bf(nx - bf2f(xh));
    short yl = f2bf(ny - bf2f(yh));
    short zl = f2bf(nz - bf2f(zh));
    short wh = f2bf(w2);
    short wl = f2bf(w2 - bf2f(wh));
    bf16x8 o0 = { xh, yh, zh, xl, yl, zl, xh, yh };
    bf16x8 o1 = { zh, wh, wl, 0, 0, 0, 0, 0 };
    char* base = wsB + (size_t)(b * 2 + dir) * 65536 + (size_t)m * 16;
    *(bf16x8*)(base)         = o0;
    *(bf16x8*)(base + 32768) = o1;
}

// ---- Main: grid (4, B_, 2), 512 threads (8 waves). Block = 512-row part x
// all 2048 cols. Wave owns 4 row-tiles; loops 128 col-tiles: 1 predicated
// 16B L2 load (B frag) + 4 MFMA + 16 v_min.
__global__ __launch_bounds__(512) void chamfer_mfma(
    const int* __restrict__ o_w, const float* __restrict__ o_pts,
    const int* __restrict__ t_w, const float* __restrict__ t_pts,
    const char* __restrict__ wsB, float* __restrict__ partials)
{
    const int part = blockIdx.x, b = blockIdx.y, dir = blockIdx.z;
    const int tid  = threadIdx.x;
    const int lane = tid & 63, wv = tid >> 6;
    const int q    = lane >> 4, c15 = lane & 15;

    const float* pa = (dir == 0) ? o_pts : t_pts;   // outer (row) side
    const int*   wa = (dir == 0) ? o_w   : t_w;
    const int rowBase = part * 512 + wv * 64;

    // A-operand frags: A[m=c15][k=q*8+j]; rows in bf16 hi/lo split.
    // k0-7: [axh,ayh,azh,axh,ayh,azh,axl,ayl]  k8-15: [azl,1,1,0...]
    const short BONE = 0x3F80;   // bf16 1.0
    bf16x8 af[4];
    #pragma unroll
    for (int rt = 0; rt < 4; ++rt) {
        int gi = b * N_ + rowBase + rt * 16 + c15;
        float ax = pa[gi * 3 + 0], ay = pa[gi * 3 + 1], az = pa[gi * 3 + 2];
        short xh = f2bf(ax), yh = f2bf(ay), zh = f2bf(az);
        short xl = f2bf(ax - bf2f(xh));
        short yl = f2bf(ay - bf2f(yh));
        short zl = f2bf(az - bf2f(zh));
        bf16x8 f0 = { xh, yh, zh, xh, yh, zh, xl, yl };
        bf16x8 f1 = { zl, BONE, BONE, 0, 0, 0, 0, 0 };
        bf16x8 fz = { 0, 0, 0, 0, 0, 0, 0, 0 };
        af[rt] = (q == 0) ? f0 : ((q == 1) ? f1 : fz);
    }

    const char* bbase = wsB + (size_t)(b * 2 + dir) * 65536
                      + (q == 1 ? 32768 : 0) + c15 * 16;

    f32x4 acc[4];
    #pragma unroll
    for (int rt = 0; rt < 4; ++rt)
        acc[rt] = (f32x4){ 3.4e38f, 3.4e38f, 3.4e38f, 3.4e38f };
    const f32x4 CZERO = (f32x4){ 0.f, 0.f, 0.f, 0.f };

    #pragma unroll 4
    for (int ct = 0; ct < 128; ++ct) {
        bf16x8 bf = { 0, 0, 0, 0, 0, 0, 0, 0 };
        if (lane < 32)                          // k>=16 lanes supply zeros
            bf = *(const bf16x8*)(bbase + ct * 256);
        #pragma unroll
        for (int rt = 0; rt < 4; ++rt) {
            f32x4 d = __builtin_amdgcn_mfma_f32_16x16x32_bf16(
                          af[rt], bf, CZERO, 0, 0, 0);
            acc[rt][0] = fminf(acc[rt][0], d[0]);
            acc[rt][1] = fminf(acc[rt][1], d[1]);
            acc[rt][2] = fminf(acc[rt][2], d[2]);
            acc[rt][3] = fminf(acc[rt][3], d[3]);
        }
    }

    // Cross-lane min over the 16 cols (xor within lane&15).
    #pragma unroll
    for (int rt = 0; rt < 4; ++rt) {
        #pragma unroll
        for (int j = 0; j < 4; ++j) {
            float v = acc[rt][j];
            v = fminf(v, __shfl_xor(v, 1, 64));
            v = fminf(v, __shfl_xor(v, 2, 64));
            v = fminf(v, __shfl_xor(v, 4, 64));
            v = fminf(v, __shfl_xor(v, 8, 64));
            acc[rt][j] = v;
        }
    }

    // Epilogue: rows live at (q,reg); lanes with c15==0 own them uniquely.
    float sum = 0.f;
    if (c15 == 0) {
        #pragma unroll
        for (int rt = 0; rt < 4; ++rt) {
            #pragma unroll
            for (int j = 0; j < 4; ++j) {
                int gi = b * N_ + rowBase + rt * 16 + q * 4 + j;
                float ax = pa[gi * 3 + 0], ay = pa[gi * 3 + 1], az = pa[gi * 3 + 2];
                float a2 = fmaf(ax, ax, fmaf(ay, ay, az * az));
                float d2 = fmaxf(a2 + acc[rt][j], 0.f);
                sum += (wa[gi] != 0) ? d2 : 0.f;
            }
        }
    }
    #pragma unroll
    for (int off = 32; off; off >>= 1) sum += __shfl_xor(sum, off, 64);
    if (lane == 0)
        partials[b * 64 + dir * 32 + part * 8 + wv] = sum;
}

// Finish: one block, 256 threads; 64 partials per batch (R3-verified shape).
__global__ __launch_bounds__(256) void chamfer_finish(
    const float* __restrict__ partials, float* __restrict__ loss)
{
    int t = threadIdx.x;
    int b = t >> 3, k = t & 7;
    const float4* p4 = (const float4*)(partials + b * 64 + k * 8);
    float4 u = p4[0], v = p4[1];
    float s = ((u.x + u.y) + (u.z + u.w)) + ((v.x + v.y) + (v.z + v.w));
    #pragma unroll
    for (int off = 4; off; off >>= 1) s += __shfl_xor(s, off, 64);
    if (k == 0) loss[b] = 0.5f * s;
}

// ---------- Fallback (ws too small): fp32 path + atomics ----------
__global__ void chamfer_zero(float* __restrict__ loss)
{
    if (threadIdx.x < B_) loss[threadIdx.x] = 0.0f;
}

__global__ __launch_bounds__(256) void chamfer_nolds(
    const int* __restrict__ o_w, const float* __restrict__ o_pts,
    const int* __restrict__ t_w, const float* __restrict__ t_pts,
    float* __restrict__ loss)
{
    const int dir  = blockIdx.z;
    const int b    = blockIdx.y;
    const int lane = threadIdx.x & 63;
    const int wv   = threadIdx.x >> 6;
    const int row0 = (blockIdx.x * 4 + wv) * 16;

    const int*   __restrict__ wa = (dir == 0) ? o_w   : t_w;
    const float* __restrict__ pa = (dir == 0) ? o_pts : t_pts;
    const int*   __restrict__ wb = (dir == 0) ? t_w   : o_w;
    const float* __restrict__ pb = (dir == 0) ? t_pts : o_pts;

    int base = __builtin_amdgcn_readfirstlane((b * N_ + row0) * 3);
    const float* rp = pa + base;
    float rx[16], ry[16], rz[16];
    #pragma unroll
    for (int r = 0; r < 16; ++r) {
        rx[r] = rp[3 * r + 0];
        ry[r] = rp[3 * r + 1];
        rz[r] = rp[3 * r + 2];
    }
    float acc[16];
    #pragma unroll
    for (int r = 0; r < 16; ++r) acc[r] = 3.4e38f;

    #pragma unroll 2
    for (int t = 0; t < M_ / 64; ++t) {
        int ib = b * M_ + t * 64 + lane;
        float bx = pb[ib * 3 + 0], by = pb[ib * 3 + 1], bz = pb[ib * 3 + 2];
        float n2 = fmaf(bx, bx, fmaf(by, by, bz * bz));
        float qw = (wb[ib] != 0) ? n2 : BIG2;
        float qx = -2.0f * bx, qy = -2.0f * by, qz = -2.0f * bz;
        #pragma unroll
        for (int r = 0; r < 16; ++r) {
            float d = fmaf(rx[r], qx, fmaf(ry[r], qy, fmaf(rz[r], qz, qw)));
            acc[r] = fminf(acc[r], d);
        }
    }
    #pragma unroll
    for (int r = 0; r < 16; ++r) {
        float v = acc[r];
        #pragma unroll
        for (int off = 32; off; off >>= 1) v = fminf(v, __shfl_xor(v, off, 64));
        acc[r] = v;
    }
    int mbase = __builtin_amdgcn_readfirstlane(b * N_ + row0);
    const int* wp = wa + mbase;
    float sum = 0.0f;
    #pragma unroll
    for (int r = 0; r < 16; ++r) {
        float a2 = fmaf(rx[r], rx[r], fmaf(ry[r], ry[r], rz[r] * rz[r]));
        float d2 = fmaxf(a2 + acc[r], 0.0f);
        sum += (wp[r] != 0) ? d2 : 0.0f;
    }
    if (lane == 0) atomicAdd(&loss[b], 0.5f * sum);
}

extern "C" void kernel_launch(void* const* d_in, const int* in_sizes, int n_in,
                              void* d_out, int out_size, void* d_ws, size_t ws_size,
                              hipStream_t stream) {
    const int*   o_w   = (const int*)  d_in[0];
    const float* o_pts = (const float*)d_in[1];
    const int*   t_w   = (const int*)  d_in[2];
    const float* t_pts = (const float*)d_in[3];
    float* loss = (float*)d_out;

    const size_t bBytes    = (size_t)64 * 65536;          // 4 MB B-frag planes
    const size_t partBytes = 2048 * sizeof(float);        // 8 KB partials

    if (ws_size >= bBytes + partBytes) {
        char*  wsB      = (char*)d_ws;
        float* partials = (float*)((char*)d_ws + bBytes);
        chamfer_prep_mfma<<<512, 256, 0, stream>>>(
            o_w, o_pts, t_w, t_pts, wsB);
        chamfer_mfma<<<dim3(4, B_, 2), 512, 0, stream>>>(
            o_w, o_pts, t_w, t_pts, wsB, partials);
        chamfer_finish<<<1, 256, 0, stream>>>(partials, loss);
    } else {
        chamfer_zero<<<1, 64, 0, stream>>>(loss);
        dim3 grid(N_ / 64, B_, 2);
        chamfer_nolds<<<grid, 256, 0, stream>>>(
            o_w, o_pts, t_w, t_pts, loss);
    }
}